// Round 1
// 429.988 us; speedup vs baseline: 1.0581x; 1.0581x over previous
//
#include <hip/hip_runtime.h>
#include <math.h>

#define L_SIG 160000
#define HOPC 128
#define FD 257
#define TDIM 1251          // (160512 - 512)/128 + 1
#define ROW 4112           // 16 * 257
#define NROWS (16 * TDIM)  // 20016 output rows
#define NBC 64             // B*C
#define NFR (NBC * TDIM)   // 80064 frames (even)
#define NPAIR (NFR / 2)    // 40032 wave-pairs

typedef float floatx4 __attribute__((ext_vector_type(4)));

// ws layout (floats): [0:2056) sv row-suffix S = [svre c=0..3 (257 each), svim c=0..3]

__global__ __launch_bounds__(256) void setup_kernel(const float* __restrict__ angle,
                                                    const float* __restrict__ mic,
                                                    float* __restrict__ tbl) {
    int tid = threadIdx.x;
    __shared__ float tdoa[4];
    if (tid == 0) {
        const float half_pi = (float)(M_PI / 2.0);
        float s90 = sinf(half_pi);
        float c90 = cosf(half_pi);
        float acc0 = 0.f, acc1 = 0.f, acc2 = 0.f, acc3 = 0.f;
        for (int b = 0; b < 16; ++b) {
            float ang = angle[b];
            float rad = -ang * (float)(M_PI / 180.0);
            float lx = cosf(rad) * s90;
            float ly = sinf(rad) * s90;
            float lz = c90;                 // DIST = 1.0
            #pragma unroll
            for (int c = 0; c < 4; ++c) {
                const float* m = mic + ((size_t)b * 4 + c) * 3;
                float dx = m[0] - lx, dy = m[1] - ly, dz = m[2] - lz;
                float s = dx * dx + dy * dy + dz * dz;
                if (c == 0) acc0 += s; else if (c == 1) acc1 += s;
                else if (c == 2) acc2 += s; else acc3 += s;
            }
        }
        float t0 = sqrtf(acc0);
        tdoa[0] = 0.0f;
        tdoa[1] = sqrtf(acc1) - t0;
        tdoa[2] = sqrtf(acc2) - t0;
        tdoa[3] = sqrtf(acc3) - t0;
    }
    __syncthreads();
    const float coef = (float)(-2.0 * M_PI * 16000.0 / (512.0 * 340.4));
    for (int i = tid; i < 4 * FD; i += 256) {
        int c = i / FD;
        int f = i - c * FD;
        float ph = coef * (float)f * tdoa[c];
        tbl[i]        = cosf(ph) * 0.5f;   // sv.re, / ||sv|| = sqrt(C) = 2
        tbl[1028 + i] = sinf(ph) * 0.5f;   // sv.im
    }
}

// 8-point complex DFT in registers (DIF split)
__device__ __forceinline__ void bfly8(float (&zr)[8], float (&zi)[8]) {
    const float C = 0.70710678118654752440f;   // sqrt(2)/2
    float sr0=zr[0]+zr[4], si0=zi[0]+zi[4], dr0=zr[0]-zr[4], di0=zi[0]-zi[4];
    float sr1=zr[1]+zr[5], si1=zi[1]+zi[5], dr1=zr[1]-zr[5], di1=zi[1]-zi[5];
    float sr2=zr[2]+zr[6], si2=zi[2]+zi[6], dr2=zr[2]-zr[6], di2=zi[2]-zi[6];
    float sr3=zr[3]+zr[7], si3=zi[3]+zi[7], dr3=zr[3]-zr[7], di3=zi[3]-zi[7];
    float t;
    t = C*(dr1+di1); di1 = C*(di1-dr1); dr1 = t;
    t = dr2; dr2 = di2; di2 = -t;
    t = C*(di3-dr3); di3 = -C*(dr3+di3); dr3 = t;
    float p0r=sr0+sr2, p0i=si0+si2, p1r=sr1+sr3, p1i=si1+si3;
    float q0r=sr0-sr2, q0i=si0-si2, q1r=sr1-sr3, q1i=si1-si3;
    zr[0]=p0r+p1r; zi[0]=p0i+p1i;
    zr[2]=q0r+q1i; zi[2]=q0i-q1r;
    zr[4]=p0r-p1r; zi[4]=p0i-p1i;
    zr[6]=q0r-q1i; zi[6]=q0i+q1r;
    p0r=dr0+dr2; p0i=di0+di2; p1r=dr1+dr3; p1i=di1+di3;
    q0r=dr0-dr2; q0i=di0-di2; q1r=dr1-dr3; q1i=di1-di3;
    zr[1]=p0r+p1r; zi[1]=p0i+p1i;
    zr[3]=q0r+q1i; zi[3]=q0i-q1r;
    zr[5]=p0r-p1r; zi[5]=p0i-p1i;
    zr[7]=q0r-q1i; zi[7]=q0i+q1r;
}

__device__ __forceinline__ void cmul(float& r, float& i, float ar, float ai, float br, float bi) {
    r = ar * br - ai * bi;
    i = ar * bi + ai * br;
}

// z_k *= w^k, k=1..7, tree-structured powers (dep depth 3)
__device__ __forceinline__ void twiddle8(float (&zr)[8], float (&zi)[8], float wr, float wi) {
    float p2r, p2i, p3r, p3i, p4r, p4i, p5r, p5i, p6r, p6i, p7r, p7i;
    cmul(p2r, p2i, wr, wi, wr, wi);
    cmul(p3r, p3i, p2r, p2i, wr, wi);
    cmul(p4r, p4i, p2r, p2i, p2r, p2i);
    cmul(p5r, p5i, p4r, p4i, wr, wi);
    cmul(p6r, p6i, p3r, p3i, p3r, p3i);
    cmul(p7r, p7i, p4r, p4i, p3r, p3i);
    float t;
    t = zr[1]*wr - zi[1]*wi;  zi[1] = zr[1]*wi + zi[1]*wr;  zr[1] = t;
    t = zr[2]*p2r - zi[2]*p2i; zi[2] = zr[2]*p2i + zi[2]*p2r; zr[2] = t;
    t = zr[3]*p3r - zi[3]*p3i; zi[3] = zr[3]*p3i + zi[3]*p3r; zr[3] = t;
    t = zr[4]*p4r - zi[4]*p4i; zi[4] = zr[4]*p4i + zi[4]*p4r; zr[4] = t;
    t = zr[5]*p5r - zi[5]*p5i; zi[5] = zr[5]*p5i + zi[5]*p5r; zr[5] = t;
    t = zr[6]*p6r - zi[6]*p6i; zi[6] = zr[6]*p6i + zi[6]*p6r; zr[6] = t;
    t = zr[7]*p7r - zi[7]*p7i; zi[7] = zr[7]*p7i + zi[7]*p7r; zr[7] = t;
}

#define PHYS(i) ((i) + ((i) >> 3))   // LDS pad: +1 float2 per 8

// One wave = 2 packed real frames -> one complex 512-FFT. No block barriers:
// each wave owns its own LDS slice; in-wave DS ordering is program order.
// Fused: the wave owning channel 0 of a row also streams the fixed 2056-float
// sv suffix into that row (eliminates the separate sv_bcast pass).
__global__ __launch_bounds__(256) void stft8_kernel(const float* __restrict__ x,
                                                    const float* __restrict__ tbl,
                                                    float* __restrict__ out) {
    __shared__ float2 exch[4][576];
    const int tid = threadIdx.x;
    const int wv  = tid >> 6;
    const int j   = tid & 63;
    const int pid = blockIdx.x * 4 + wv;
    const int fid0 = 2 * pid;
    const int fid1 = fid0 + 1;
    const int t0 = fid0 % TDIM, bc0 = fid0 / TDIM;
    const int t1 = fid1 % TDIM, bc1 = fid1 / TDIM;

    // hann[j+64r] = 0.5 - 0.5*cos(theta + r*pi/4), theta = pi*j/256
    const float PI_256 = 0.012271846303085129838f;
    float sj, cj;
    __sincosf((float)j * PI_256, &sj, &cj);
    const float R2 = 0.70710678118654752440f;
    float cv[8];
    cv[0] = cj;            cv[1] = (cj - sj) * R2;
    cv[2] = -sj;           cv[3] = (-cj - sj) * R2;
    cv[4] = -cj;           cv[5] = (sj - cj) * R2;
    cv[6] = sj;            cv[7] = (cj + sj) * R2;

    const float* xs0 = x + (size_t)bc0 * L_SIG;
    const float* xs1 = x + (size_t)bc1 * L_SIG;
    const int g0 = t0 * HOPC - 256 + j;
    const int g1 = t1 * HOPC - 256 + j;
    float zr[8], zi[8];

    // Interior frames (t in [2,1248]) need no reflect arithmetic — wave-uniform.
    const bool in0 = (t0 >= 2) && (t0 < 1249);
    const bool in1 = (t1 >= 2) && (t1 < 1249);
    if (in0 && in1) {
        #pragma unroll
        for (int r = 0; r < 8; ++r) {
            float w = 0.5f - 0.5f * cv[r];
            zr[r] = xs0[g0 + 64 * r] * w;
            zi[r] = xs1[g1 + 64 * r] * w;
        }
    } else {
        #pragma unroll
        for (int r = 0; r < 8; ++r) {
            int a0 = g0 + 64 * r; a0 = (a0 < 0) ? -a0 : a0; if (a0 >= L_SIG) a0 = 2 * L_SIG - 2 - a0;
            int a1 = g1 + 64 * r; a1 = (a1 < 0) ? -a1 : a1; if (a1 >= L_SIG) a1 = 2 * L_SIG - 2 - a1;
            float w = 0.5f - 0.5f * cv[r];
            zr[r] = xs0[a0] * w;
            zi[r] = xs1[a1] * w;
        }
    }

    float2* buf = exch[wv];

    // stage 0 (m=1): w = e^{-2pi i j/512} = (cj, -sj)
    bfly8(zr, zi);
    twiddle8(zr, zi, cj, -sj);
    #pragma unroll
    for (int k = 0; k < 8; ++k) {
        int idx = 8 * j + k;
        buf[PHYS(idx)] = make_float2(zr[k], zi[k]);
    }
    #pragma unroll
    for (int r = 0; r < 8; ++r) {
        int idx = j + 64 * r;
        float2 v = buf[PHYS(idx)];
        zr[r] = v.x; zi[r] = v.y;
    }

    // stage 1 (m=8): w = e^{-2pi i (j&~7)/512}
    bfly8(zr, zi);
    float s1v, c1v;
    __sincosf((float)(j & ~7) * PI_256, &s1v, &c1v);
    twiddle8(zr, zi, c1v, -s1v);
    #pragma unroll
    for (int k = 0; k < 8; ++k) {
        int idx = 64 * (j >> 3) + (j & 7) + 8 * k;
        buf[PHYS(idx)] = make_float2(zr[k], zi[k]);
    }
    #pragma unroll
    for (int r = 0; r < 8; ++r) {
        int idx = j + 64 * r;
        float2 v = buf[PHYS(idx)];
        zr[r] = v.x; zi[r] = v.y;
    }

    // stage 2 (m=64): butterfly only -> Z[j + 64k]
    bfly8(zr, zi);

    // conj partner Z[(512-f)&511]: lane (64-j)&63, reg 7-k (j>=1) or (8-k)&7 (j==0)
    const int srcl = (64 - j) & 63;
    float pr_[8], pi_[8];
    #pragma unroll
    for (int m = 0; m < 8; ++m) {
        pr_[m] = __shfl(zr[m], srcl, 64);
        pi_[m] = __shfl(zi[m], srcl, 64);
    }

    const int b0 = bc0 >> 2, c0 = bc0 & 3;
    const int b1 = bc1 >> 2, c1 = bc1 & 3;
    const size_t base0 = ((size_t)b0 * TDIM + t0) * ROW + (size_t)c0 * FD;
    const size_t base1 = ((size_t)b1 * TDIM + t1) * ROW + (size_t)c1 * FD;
    const bool l0 = (j == 0);

    #pragma unroll
    for (int k = 0; k < 5; ++k) {
        float Pr = l0 ? pr_[(8 - k) & 7] : pr_[7 - k];
        float Pi = l0 ? pi_[(8 - k) & 7] : pi_[7 - k];
        // F0 = (Z + conj(P))/2 ; F1 = -i(Z - conj(P))/2
        float F0r = 0.5f * (zr[k] + Pr);
        float F0i = 0.5f * (zi[k] - Pi);
        float F1r = 0.5f * (zi[k] + Pi);
        float F1i = 0.5f * (Pr - zr[k]);
        int f = j + 64 * k;
        if (k < 4 || l0) {          // f <= 256
            __builtin_nontemporal_store(F0r, out + base0 + f);
            __builtin_nontemporal_store(F0i, out + base0 + 1028 + f);
            __builtin_nontemporal_store(F1r, out + base1 + f);
            __builtin_nontemporal_store(F1i, out + base1 + 1028 + f);
        }
    }

    // Fused sv suffix: the c==0 wave of each row writes floats [2056,4112) of
    // that row from the 8 KB table (L1-resident). Wave-uniform branch.
    const floatx4* S4 = (const floatx4*)tbl;        // 514 float4s
    if (c0 == 0) {
        floatx4* dst = (floatx4*)(out + base0 + 2056);   // base0 == row*ROW here
        #pragma unroll
        for (int it = 0; it < 8; ++it) {
            int i4 = 64 * it + j;
            __builtin_nontemporal_store(S4[i4], dst + i4);
        }
        if (j < 2)
            __builtin_nontemporal_store(S4[512 + j], dst + 512 + j);
    }
    if (c1 == 0) {
        floatx4* dst = (floatx4*)(out + base1 + 2056);
        #pragma unroll
        for (int it = 0; it < 8; ++it) {
            int i4 = 64 * it + j;
            __builtin_nontemporal_store(S4[i4], dst + i4);
        }
        if (j < 2)
            __builtin_nontemporal_store(S4[512 + j], dst + 512 + j);
    }
}

extern "C" void kernel_launch(void* const* d_in, const int* in_sizes, int n_in,
                              void* d_out, int out_size, void* d_ws, size_t ws_size,
                              hipStream_t stream) {
    const float* x     = (const float*)d_in[0];
    const float* angle = (const float*)d_in[1];
    const float* mic   = (const float*)d_in[2];
    float* out = (float*)d_out;
    float* tbl = (float*)d_ws;

    setup_kernel<<<1, 256, 0, stream>>>(angle, mic, tbl);
    stft8_kernel<<<NPAIR / 4, 256, 0, stream>>>(x, tbl, out);
}

// Round 2
// 367.669 us; speedup vs baseline: 1.2374x; 1.1695x over previous
//
#include <hip/hip_runtime.h>
#include <math.h>

#define L_SIG 160000
#define HOPC 128
#define FD 257
#define TDIM 1251          // (160512 - 512)/128 + 1
#define ROW 4112           // 16 * 257
#define NROWS (16 * TDIM)  // 20016 output rows

typedef float floatx4 __attribute__((ext_vector_type(4)));

// ws layout (floats): [0:2056) sv row-suffix S = [svre c=0..3 (257 each), svim c=0..3]

__global__ __launch_bounds__(256) void setup_kernel(const float* __restrict__ angle,
                                                    const float* __restrict__ mic,
                                                    float* __restrict__ tbl) {
    int tid = threadIdx.x;
    __shared__ float tdoa[4];
    if (tid == 0) {
        const float half_pi = (float)(M_PI / 2.0);
        float s90 = sinf(half_pi);
        float c90 = cosf(half_pi);
        float acc0 = 0.f, acc1 = 0.f, acc2 = 0.f, acc3 = 0.f;
        for (int b = 0; b < 16; ++b) {
            float ang = angle[b];
            float rad = -ang * (float)(M_PI / 180.0);
            float lx = cosf(rad) * s90;
            float ly = sinf(rad) * s90;
            float lz = c90;                 // DIST = 1.0
            #pragma unroll
            for (int c = 0; c < 4; ++c) {
                const float* m = mic + ((size_t)b * 4 + c) * 3;
                float dx = m[0] - lx, dy = m[1] - ly, dz = m[2] - lz;
                float s = dx * dx + dy * dy + dz * dz;
                if (c == 0) acc0 += s; else if (c == 1) acc1 += s;
                else if (c == 2) acc2 += s; else acc3 += s;
            }
        }
        float t0 = sqrtf(acc0);
        tdoa[0] = 0.0f;
        tdoa[1] = sqrtf(acc1) - t0;
        tdoa[2] = sqrtf(acc2) - t0;
        tdoa[3] = sqrtf(acc3) - t0;
    }
    __syncthreads();
    const float coef = (float)(-2.0 * M_PI * 16000.0 / (512.0 * 340.4));
    for (int i = tid; i < 4 * FD; i += 256) {
        int c = i / FD;
        int f = i - c * FD;
        float ph = coef * (float)f * tdoa[c];
        tbl[i]        = cosf(ph) * 0.5f;   // sv.re, / ||sv|| = sqrt(C) = 2
        tbl[1028 + i] = sinf(ph) * 0.5f;   // sv.im
    }
}

// 8-point complex DFT in registers (DIF split)
__device__ __forceinline__ void bfly8(float (&zr)[8], float (&zi)[8]) {
    const float C = 0.70710678118654752440f;   // sqrt(2)/2
    float sr0=zr[0]+zr[4], si0=zi[0]+zi[4], dr0=zr[0]-zr[4], di0=zi[0]-zi[4];
    float sr1=zr[1]+zr[5], si1=zi[1]+zi[5], dr1=zr[1]-zr[5], di1=zi[1]-zi[5];
    float sr2=zr[2]+zr[6], si2=zi[2]+zi[6], dr2=zr[2]-zr[6], di2=zi[2]-zi[6];
    float sr3=zr[3]+zr[7], si3=zi[3]+zi[7], dr3=zr[3]-zr[7], di3=zi[3]-zi[7];
    float t;
    t = C*(dr1+di1); di1 = C*(di1-dr1); dr1 = t;
    t = dr2; dr2 = di2; di2 = -t;
    t = C*(di3-dr3); di3 = -C*(dr3+di3); dr3 = t;
    float p0r=sr0+sr2, p0i=si0+si2, p1r=sr1+sr3, p1i=si1+si3;
    float q0r=sr0-sr2, q0i=si0-si2, q1r=sr1-sr3, q1i=si1-si3;
    zr[0]=p0r+p1r; zi[0]=p0i+p1i;
    zr[2]=q0r+q1i; zi[2]=q0i-q1r;
    zr[4]=p0r-p1r; zi[4]=p0i-p1i;
    zr[6]=q0r-q1i; zi[6]=q0i+q1r;
    p0r=dr0+dr2; p0i=di0+di2; p1r=dr1+dr3; p1i=di1+di3;
    q0r=dr0-dr2; q0i=di0-di2; q1r=dr1-dr3; q1i=di1-di3;
    zr[1]=p0r+p1r; zi[1]=p0i+p1i;
    zr[3]=q0r+q1i; zi[3]=q0i-q1r;
    zr[5]=p0r-p1r; zi[5]=p0i-p1i;
    zr[7]=q0r-q1i; zi[7]=q0i+q1r;
}

__device__ __forceinline__ void cmul(float& r, float& i, float ar, float ai, float br, float bi) {
    r = ar * br - ai * bi;
    i = ar * bi + ai * br;
}

// z_k *= w^k, k=1..7, tree-structured powers (dep depth 3)
__device__ __forceinline__ void twiddle8(float (&zr)[8], float (&zi)[8], float wr, float wi) {
    float p2r, p2i, p3r, p3i, p4r, p4i, p5r, p5i, p6r, p6i, p7r, p7i;
    cmul(p2r, p2i, wr, wi, wr, wi);
    cmul(p3r, p3i, p2r, p2i, wr, wi);
    cmul(p4r, p4i, p2r, p2i, p2r, p2i);
    cmul(p5r, p5i, p4r, p4i, wr, wi);
    cmul(p6r, p6i, p3r, p3i, p3r, p3i);
    cmul(p7r, p7i, p4r, p4i, p3r, p3i);
    float t;
    t = zr[1]*wr - zi[1]*wi;  zi[1] = zr[1]*wi + zi[1]*wr;  zr[1] = t;
    t = zr[2]*p2r - zi[2]*p2i; zi[2] = zr[2]*p2i + zi[2]*p2r; zr[2] = t;
    t = zr[3]*p3r - zi[3]*p3i; zi[3] = zr[3]*p3i + zi[3]*p3r; zr[3] = t;
    t = zr[4]*p4r - zi[4]*p4i; zi[4] = zr[4]*p4i + zi[4]*p4r; zr[4] = t;
    t = zr[5]*p5r - zi[5]*p5i; zi[5] = zr[5]*p5i + zi[5]*p5r; zr[5] = t;
    t = zr[6]*p6r - zi[6]*p6i; zi[6] = zr[6]*p6i + zi[6]*p6r; zr[6] = t;
    t = zr[7]*p7r - zi[7]*p7i; zi[7] = zr[7]*p7i + zi[7]*p7r; zr[7] = t;
}

#define PHYS(i) ((i) + ((i) >> 3))   // LDS pad: +1 float2 per 8

// One packed real-pair FFT-512: inputs xs0 + i*xs1 (two channels, same frame t),
// outputs the rfft halves F0 (=FFT(xs0)) and F1 (=FFT(xs1)) for f = j + 64k,
// k = 0..4 (k==4 valid only for lane j==0, f=256). Wave-private LDS via buf.
__device__ __forceinline__ void fft512_pair(const float* __restrict__ xs0,
                                            const float* __restrict__ xs1,
                                            const int (&a)[8], const float (&w8)[8],
                                            float cj, float sj, float c1v, float s1v,
                                            int j, float2* buf,
                                            float (&F0r)[5], float (&F0i)[5],
                                            float (&F1r)[5], float (&F1i)[5]) {
    float zr[8], zi[8];
    #pragma unroll
    for (int r = 0; r < 8; ++r) {
        zr[r] = xs0[a[r]] * w8[r];
        zi[r] = xs1[a[r]] * w8[r];
    }

    // stage 0 (m=1): w = e^{-2pi i j/512} = (cj, -sj)
    bfly8(zr, zi);
    twiddle8(zr, zi, cj, -sj);
    #pragma unroll
    for (int k = 0; k < 8; ++k) buf[PHYS(8 * j + k)] = make_float2(zr[k], zi[k]);
    #pragma unroll
    for (int r = 0; r < 8; ++r) {
        float2 v = buf[PHYS(j + 64 * r)];
        zr[r] = v.x; zi[r] = v.y;
    }

    // stage 1 (m=8): w = e^{-2pi i (j&~7)/512}
    bfly8(zr, zi);
    twiddle8(zr, zi, c1v, -s1v);
    #pragma unroll
    for (int k = 0; k < 8; ++k) buf[PHYS(64 * (j >> 3) + (j & 7) + 8 * k)] = make_float2(zr[k], zi[k]);
    #pragma unroll
    for (int r = 0; r < 8; ++r) {
        float2 v = buf[PHYS(j + 64 * r)];
        zr[r] = v.x; zi[r] = v.y;
    }

    // stage 2 (m=64): butterfly only -> Z[j + 64k]
    bfly8(zr, zi);

    // conj partner Z[(512-f)&511]: lane (64-j)&63, reg 7-k (j>=1) or (8-k)&7 (j==0)
    const int srcl = (64 - j) & 63;
    float pr_[8], pi_[8];
    #pragma unroll
    for (int m = 0; m < 8; ++m) {
        pr_[m] = __shfl(zr[m], srcl, 64);
        pi_[m] = __shfl(zi[m], srcl, 64);
    }
    const bool l0 = (j == 0);
    #pragma unroll
    for (int k = 0; k < 5; ++k) {
        float Pr = l0 ? pr_[(8 - k) & 7] : pr_[7 - k];
        float Pi = l0 ? pi_[(8 - k) & 7] : pi_[7 - k];
        // F0 = (Z + conj(P))/2 ; F1 = -i(Z - conj(P))/2
        F0r[k] = 0.5f * (zr[k] + Pr);
        F0i[k] = 0.5f * (zi[k] - Pi);
        F1r[k] = 0.5f * (zi[k] + Pi);
        F1i[k] = 0.5f * (Pr - zr[k]);
    }
}

// One wave = one output row (b,t) = all 4 channels = 2 packed FFTs.
// Row is assembled in a per-wave LDS staging buffer and written as ONE
// contiguous 16448-B dwordx4 NT stream (+ sv suffix from the 8 KB table).
// Consecutive waves write adjacent rows -> streaming write locality.
__global__ __launch_bounds__(256) void stft_row_kernel(const float* __restrict__ x,
                                                       const float* __restrict__ tbl,
                                                       float* __restrict__ out) {
    __shared__ floatx4 stg4[4][516];            // 516*16 = 8256 B per wave (>= 2056 floats)
    const int tid = threadIdx.x;
    const int wv  = tid >> 6;
    const int j   = tid & 63;
    const int wid = blockIdx.x * 4 + wv;        // output row id, 0..20015
    const int b = wid / TDIM;
    const int t = wid - b * TDIM;

    // hann[j+64r] = 0.5 - 0.5*cos(theta + r*pi/4), theta = pi*j/256
    const float PI_256 = 0.012271846303085129838f;
    float sj, cj;
    __sincosf((float)j * PI_256, &sj, &cj);
    const float R2 = 0.70710678118654752440f;
    float w8[8];
    w8[0] = 0.5f - 0.5f * cj;
    w8[1] = 0.5f - 0.5f * ((cj - sj) * R2);
    w8[2] = 0.5f + 0.5f * sj;
    w8[3] = 0.5f - 0.5f * ((-cj - sj) * R2);
    w8[4] = 0.5f + 0.5f * cj;
    w8[5] = 0.5f - 0.5f * ((sj - cj) * R2);
    w8[6] = 0.5f - 0.5f * sj;
    w8[7] = 0.5f - 0.5f * ((cj + sj) * R2);
    float s1v, c1v;
    __sincosf((float)(j & ~7) * PI_256, &s1v, &c1v);

    // reflect-padded signal indices, shared by all 4 channels (same t)
    const int g = t * HOPC - 256 + j;
    int a[8];
    #pragma unroll
    for (int r = 0; r < 8; ++r) {
        int ar = g + 64 * r;
        ar = (ar < 0) ? -ar : ar;
        if (ar >= L_SIG) ar = 2 * L_SIG - 2 - ar;
        a[r] = ar;
    }

    float* stg  = (float*)&stg4[wv][0];
    float2* buf = (float2*)stg;                 // FFT exchange aliases staging (dead by staging time)

    const float* xb = x + (size_t)b * 4 * L_SIG;
    float A0r[5], A0i[5], A1r[5], A1i[5];       // channels 0,1
    float B0r[5], B0i[5], B1r[5], B1i[5];       // channels 2,3
    fft512_pair(xb,             xb + L_SIG,     a, w8, cj, sj, c1v, s1v, j, buf, A0r, A0i, A1r, A1i);
    fft512_pair(xb + 2 * L_SIG, xb + 3 * L_SIG, a, w8, cj, sj, c1v, s1v, j, buf, B0r, B0i, B1r, B1i);

    // stage the full row prefix [0:2056): c0re c1re c2re c3re | c0im c1im c2im c3im
    #pragma unroll
    for (int k = 0; k < 5; ++k) {
        int f = j + 64 * k;
        if (k < 4 || j == 0) {                  // f <= 256
            stg[f]        = A0r[k];
            stg[257 + f]  = A1r[k];
            stg[514 + f]  = B0r[k];
            stg[771 + f]  = B1r[k];
            stg[1028 + f] = A0i[k];
            stg[1285 + f] = A1i[k];
            stg[1542 + f] = B0i[k];
            stg[1799 + f] = B1i[k];
        }
    }

    // sweep: one contiguous row store. prefix [0:2056) from LDS, suffix [2056:4112) from tbl.
    const floatx4* sp = (const floatx4*)stg;
    floatx4* dst = (floatx4*)(out + (size_t)wid * ROW);   // row base, 16448 B, 16-aligned
    #pragma unroll
    for (int it = 0; it < 8; ++it) {
        int i4 = 64 * it + j;
        __builtin_nontemporal_store(sp[i4], dst + i4);
    }
    if (j < 2) __builtin_nontemporal_store(sp[512 + j], dst + 512 + j);

    const floatx4* T4 = (const floatx4*)tbl;              // 514 float4s, L1-resident
    #pragma unroll
    for (int it = 0; it < 8; ++it) {
        int i4 = 64 * it + j;
        __builtin_nontemporal_store(T4[i4], dst + 514 + i4);
    }
    if (j < 2) __builtin_nontemporal_store(T4[512 + j], dst + 514 + 512 + j);
}

extern "C" void kernel_launch(void* const* d_in, const int* in_sizes, int n_in,
                              void* d_out, int out_size, void* d_ws, size_t ws_size,
                              hipStream_t stream) {
    const float* x     = (const float*)d_in[0];
    const float* angle = (const float*)d_in[1];
    const float* mic   = (const float*)d_in[2];
    float* out = (float*)d_out;
    float* tbl = (float*)d_ws;

    setup_kernel<<<1, 256, 0, stream>>>(angle, mic, tbl);
    stft_row_kernel<<<NROWS / 4, 256, 0, stream>>>(x, tbl, out);
}